// Round 3
// baseline (467.201 us; speedup 1.0000x reference)
//
#include <hip/hip_runtime.h>
#include <hip/hip_bf16.h>

// GQA: B=2, T=2048, C=2048, H=32, KV=8, D=64, n_rep=4, causal, RoPE base 1e4.
// Round 3: flash restructured — paired q-tiles (uniform work), single-barrier
// double-buffered K/V staging, raw v_exp + perm-packed P, packed y stores.

typedef __hip_bfloat16 bf16_t;
typedef __bf16 bf16x8 __attribute__((ext_vector_type(8)));
typedef float f32x4 __attribute__((ext_vector_type(4)));

#define AS1 __attribute__((address_space(1)))
#define AS3 __attribute__((address_space(3)))

__device__ __forceinline__ void gload_lds16(const void* g, void* l) {
  __builtin_amdgcn_global_load_lds((const AS1 unsigned int*)g,
                                   (AS3 unsigned int*)l, 16, 0, 0);
}

__device__ __forceinline__ float fast_exp2(float x) {
#if __has_builtin(__builtin_amdgcn_exp2f)
  return __builtin_amdgcn_exp2f(x);
#else
  return exp2f(x);
#endif
}

__device__ __forceinline__ unsigned int pack_bf16_rnd(unsigned int u0, unsigned int u1) {
  // round-to-nearest(ties away) both fp32 bit patterns, pack high halves
  u0 += 0x8000u; u1 += 0x8000u;
#if __has_builtin(__builtin_amdgcn_perm)
  return __builtin_amdgcn_perm(u1, u0, 0x07060302u);
#else
  return (u1 & 0xffff0000u) | (u0 >> 16);
#endif
}

__device__ __forceinline__ void store_out(float* p, float v) { *p = v; }
__device__ __forceinline__ void store_out(bf16_t* p, float v) { *p = __float2bfloat16(v); }

// ---------------- cast x (fp32 -> bf16), vectorized ----------------
__global__ void cast_f32_bf16(const float* __restrict__ src, bf16_t* __restrict__ dst, int n4) {
  int i = blockIdx.x * blockDim.x + threadIdx.x;
  if (i >= n4) return;
  float4 v = ((const float4*)src)[i];
  bf16_t o[4] = {__float2bfloat16(v.x), __float2bfloat16(v.y),
                 __float2bfloat16(v.z), __float2bfloat16(v.w)};
  ((ushort4*)dst)[i] = *(ushort4*)o;
}

// ------------- transpose+cast weight: W[2048][ncols] f32 -> dst[n][2048] bf16 -------------
__global__ void wtrans_cast(const float* __restrict__ W, bf16_t* __restrict__ dst, int ncols) {
  __shared__ float tile[32][33];
  int tx = threadIdx.x, ty = threadIdx.y;
  int n0 = blockIdx.x * 32, k0 = blockIdx.y * 32;
#pragma unroll
  for (int i = 0; i < 4; ++i)
    tile[ty + 8 * i][tx] = W[(long)(k0 + ty + 8 * i) * ncols + n0 + tx];
  __syncthreads();
#pragma unroll
  for (int i = 0; i < 4; ++i)
    dst[(long)(n0 + ty + 8 * i) * 2048 + k0 + tx] = __float2bfloat16(tile[tx][ty + 8 * i]);
}

// ---------------- RoPE in-place, b128 vectorized ----------------
// q outputs pre-scaled by 0.125 (softmax scale) * log2(e) so flash uses raw exp2.
__global__ void rope_kernel(bf16_t* __restrict__ qkv) {
  int i = blockIdx.x * 256 + threadIdx.x;   // [row(4096)][hp(40)][oct(4)]
  int oct = i & 3;
  int rem = i >> 2;
  int hp = rem % 40;
  int row = rem / 40;
  int t = row & 2047;
  int colbase = (hp < 32) ? (hp * 64) : (2048 + (hp - 32) * 64);
  long base = (long)row * 3072 + colbase + oct * 8;
  bf16x8 x1 = *(bf16x8*)(qkv + base);
  bf16x8 x2 = *(bf16x8*)(qkv + base + 32);
  float sc = (hp < 32) ? 0.18033688011112043f : 1.0f;  // 0.125*log2(e) for q
  bf16x8 o1, o2;
#pragma unroll
  for (int jj = 0; jj < 8; ++jj) {
    int d = oct * 8 + jj;
    float inv_freq = exp2f(-(float)d * 0.4152410118074032f); // log2(10000)/32
    float ang = (float)t * inv_freq;
    float sv, cv;
    sincosf(ang, &sv, &cv);   // args up to ~2047 rad exceed HW v_sin range
    float a = __bfloat162float(((const __hip_bfloat16*)&x1)[jj]);
    float b = __bfloat162float(((const __hip_bfloat16*)&x2)[jj]);
    ((__hip_bfloat16*)&o1)[jj] = __float2bfloat16((a * cv - b * sv) * sc);
    ((__hip_bfloat16*)&o2)[jj] = __float2bfloat16((a * sv + b * cv) * sc);
  }
  *(bf16x8*)(qkv + base) = o1;
  *(bf16x8*)(qkv + base + 32) = o2;
}

// ---------------- V transpose: qkv v-cols -> vt[(b*8+kv)*64 + d][T] ----------------
__global__ void transpose_v(const bf16_t* __restrict__ qkv, bf16_t* __restrict__ vt) {
  __shared__ bf16_t tile[32][33];
  int tx = threadIdx.x, ty = threadIdx.y;
  int t0 = blockIdx.x * 32, d0 = blockIdx.y * 32, bk = blockIdx.z;
  int bb = bk >> 3, kv = bk & 7;
  const bf16_t* src = qkv + (long)(bb * 2048) * 3072 + 2560 + kv * 64;
#pragma unroll
  for (int i = 0; i < 4; ++i)
    tile[ty + 8 * i][tx] = src[(long)(t0 + ty + 8 * i) * 3072 + d0 + tx];
  __syncthreads();
#pragma unroll
  for (int i = 0; i < 4; ++i)
    vt[((long)bk * 64 + d0 + ty + 8 * i) * 2048 + t0 + tx] = tile[tx][ty + 8 * i];
}

// ---------------- GEMM: C[M][N] = A[M][K] * Bt[N][K]^T, bf16 in, fp32 acc ----------------
template <typename OutT>
__global__ __launch_bounds__(256, 2)
void gemm_bt(const bf16_t* __restrict__ A, const bf16_t* __restrict__ Bt,
             OutT* __restrict__ C, int M, int N, int K) {
  __shared__ __align__(16) bf16_t As[128 * 64];
  __shared__ __align__(16) bf16_t Bs[128 * 64];
  const int tid = threadIdx.x;
  const int wave = tid >> 6, lane = tid & 63, g = lane >> 4, l15 = lane & 15;
  const int m0 = blockIdx.y * 128, n0 = blockIdx.x * 128;
  const int mw = (wave >> 1) * 64, nw = (wave & 1) * 64;
  const bf16_t* Ab = A + (long)m0 * K;
  const bf16_t* Bb = Bt + (long)n0 * K;
  f32x4 acc[4][4] = {};
  const int nkt = K >> 6;
  for (int kt = 0; kt < nkt; ++kt) {
    __syncthreads();
#pragma unroll
    for (int i = 0; i < 4; ++i) {
      int c = i * 256 + tid;
      int row = c >> 3, pos = c & 7;
      int gcol = ((pos ^ (row & 7)) * 8);
      gload_lds16(Ab + (long)row * K + kt * 64 + gcol, &As[c * 8]);
      gload_lds16(Bb + (long)row * K + kt * 64 + gcol, &Bs[c * 8]);
    }
    __syncthreads();
#pragma unroll
    for (int ks = 0; ks < 2; ++ks) {
      bf16x8 af[4], bq[4];
#pragma unroll
      for (int i = 0; i < 4; ++i) {
        int pos = ((ks * 4 + g) ^ (l15 & 7)) * 8;
        af[i] = *(const bf16x8*)&As[(mw + i * 16 + l15) * 64 + pos];
        bq[i] = *(const bf16x8*)&Bs[(nw + i * 16 + l15) * 64 + pos];
      }
#pragma unroll
      for (int i = 0; i < 4; ++i)
#pragma unroll
        for (int j = 0; j < 4; ++j)
          acc[i][j] = __builtin_amdgcn_mfma_f32_16x16x32_bf16(af[i], bq[j], acc[i][j], 0, 0, 0);
    }
  }
#pragma unroll
  for (int i = 0; i < 4; ++i)
#pragma unroll
    for (int j = 0; j < 4; ++j) {
      int r = m0 + mw + i * 16 + g * 4;
      int cn = n0 + nw + j * 16 + l15;
#pragma unroll
      for (int ii = 0; ii < 4; ++ii)
        store_out(&C[(long)(r + ii) * N + cn], acc[i][j][ii]);
    }
}

// ---------------- Flash attention: paired q-tiles + dbuf staging ----------------
// Block j owns q-tiles qtA=j and qtB=15-j -> exactly 17 tile-computes/block.
// Per kt: sync -> prefetch kt+1 into buf^1 -> compute buf (load hides under compute).
// S^T = mfma(kf, qf) C-layout (q=lane&15) -> packed P write; l via ones-MFMA.
// LDS: Ks 2x16K + Vs 2x16K + Ps 16K = 80KB -> 2 blocks/CU (grid 512 = exactly 2/CU).
__global__ __launch_bounds__(256, 2)
void flash_attn(const bf16_t* __restrict__ qkv, const bf16_t* __restrict__ vt,
                bf16_t* __restrict__ y) {
  constexpr int T = 2048, LDQ = 3072, NQT = 16;
  __shared__ __align__(16) bf16_t Ks[2][128 * 64];   // [kk][d], chunk-swizzled
  __shared__ __align__(16) bf16_t Vs[2][64 * 128];   // [d][kk], chunk-swizzled
  __shared__ __align__(16) bf16_t Ps[4][2][32 * 32]; // per-wave, per-tile P
  const int tid = threadIdx.x, wave = tid >> 6, lane = tid & 63, g = lane >> 4, l15 = lane & 15;
  const int j = blockIdx.x, h = blockIdx.y, b = blockIdx.z;
  const int qtA = j, qtB = NQT - 1 - j, ktmax = qtB;
  const int kvh = h >> 2;
  const bf16_t* kbase = qkv + (long)(b * T) * LDQ + 2048 + kvh * 64;
  const bf16_t* vbase = vt + (long)((b * 8 + kvh) * 64) * T;

  // Q fragments (B-operand layout: n=q=l15, kdim=g*8+j)
  bf16x8 qfA[2][2], qfB[2][2];
  {
    const bf16_t* qa = qkv + (long)(b * T + qtA * 128) * LDQ + h * 64;
    const bf16_t* qb = qkv + (long)(b * T + qtB * 128) * LDQ + h * 64;
#pragma unroll
    for (int ms = 0; ms < 2; ++ms)
#pragma unroll
      for (int hh = 0; hh < 2; ++hh) {
        long off = (long)(wave * 32 + ms * 16 + l15) * LDQ + hh * 32 + g * 8;
        qfA[ms][hh] = *(const bf16x8*)(qa + off);
        qfB[ms][hh] = *(const bf16x8*)(qb + off);
      }
  }

  bf16x8 onef;
#pragma unroll
  for (int i = 0; i < 8; ++i) onef[i] = (__bf16)1.0f;

  f32x4 oA[2][4] = {}, oB[2][4] = {};
  f32x4 laccA[2] = {}, laccB[2] = {};
  const int sw = (l15 >> 1) & 3;
  const f32x4 fz = {0.f, 0.f, 0.f, 0.f};

  auto stage = [&](int kt, int buf) {
#pragma unroll
    for (int i = 0; i < 4; ++i) {
      int c = i * 256 + tid;
      { int row = c >> 3, pos = c & 7;
        gload_lds16(kbase + (long)(kt * 128 + row) * LDQ + ((pos ^ (row & 7)) * 8),
                    &Ks[buf][c * 8]); }
      { int row = c >> 4, pos = c & 15;
        gload_lds16(vbase + (long)row * T + kt * 128 + ((pos ^ (row & 15)) * 8),
                    &Vs[buf][c * 8]); }
    }
  };

  // P conversion: exp2 -> mask -> RNTA-pack -> per-wave LDS -> A-fragment + row-sum MFMA
  auto pconv = [&](f32x4 (&s)[2][2], bool diag, bf16_t* Pw, bf16x8 (&pf)[2],
                   f32x4 (&lacc)[2], int ks) {
#pragma unroll
    for (int ms = 0; ms < 2; ++ms) {
#pragma unroll
      for (int nsl = 0; nsl < 2; ++nsl) {
        unsigned int u[4];
#pragma unroll
        for (int ii = 0; ii < 4; ++ii) {
          float p = fast_exp2(s[ms][nsl][ii]);
          if (diag && (ks * 32 + nsl * 16 + g * 4 + ii > wave * 32 + ms * 16 + l15)) p = 0.f;
          u[ii] = __builtin_bit_cast(unsigned int, p);
        }
        uint2 dw;
        dw.x = pack_bf16_rnd(u[0], u[1]);
        dw.y = pack_bf16_rnd(u[2], u[3]);
        int pp = (nsl * 2 + (g >> 1)) ^ sw;
        *(uint2*)&Pw[(ms * 16 + l15) * 32 + pp * 8 + (g & 1) * 4] = dw;
      }
      pf[ms] = *(const bf16x8*)&Pw[(ms * 16 + l15) * 32 + ((g ^ sw) * 8)];
      lacc[ms] = __builtin_amdgcn_mfma_f32_16x16x32_bf16(pf[ms], onef, lacc[ms], 0, 0, 0);
    }
  };

  stage(0, 0);
  for (int kt = 0; kt <= ktmax; ++kt) {
    __syncthreads();               // drains vmcnt -> buf[kt&1] ready; buf^1 free
    if (kt < ktmax) stage(kt + 1, (kt + 1) & 1);
    const bf16_t* Kc = Ks[kt & 1];
    const bf16_t* Vc = Vs[kt & 1];
    const bool doA = (kt <= qtA);
    const bool dgA = (kt == qtA), dgB = (kt == ktmax);

#pragma unroll
    for (int ks = 0; ks < 4; ++ks) {
      bf16x8 kf[2][2];
#pragma unroll
      for (int nsl = 0; nsl < 2; ++nsl) {
        int krow = ks * 32 + nsl * 16 + l15;
        kf[nsl][0] = *(const bf16x8*)&Kc[krow * 64 + ((g ^ (l15 & 7)) * 8)];
        kf[nsl][1] = *(const bf16x8*)&Kc[krow * 64 + (((4 + g) ^ (l15 & 7)) * 8)];
      }
      f32x4 sB[2][2], sA[2][2];
#pragma unroll
      for (int nsl = 0; nsl < 2; ++nsl)
#pragma unroll
        for (int ms = 0; ms < 2; ++ms) {
          f32x4 t = __builtin_amdgcn_mfma_f32_16x16x32_bf16(kf[nsl][0], qfB[ms][0], fz, 0, 0, 0);
          sB[ms][nsl] = __builtin_amdgcn_mfma_f32_16x16x32_bf16(kf[nsl][1], qfB[ms][1], t, 0, 0, 0);
        }
      if (doA) {
#pragma unroll
        for (int nsl = 0; nsl < 2; ++nsl)
#pragma unroll
          for (int ms = 0; ms < 2; ++ms) {
            f32x4 t = __builtin_amdgcn_mfma_f32_16x16x32_bf16(kf[nsl][0], qfA[ms][0], fz, 0, 0, 0);
            sA[ms][nsl] = __builtin_amdgcn_mfma_f32_16x16x32_bf16(kf[nsl][1], qfA[ms][1], t, 0, 0, 0);
          }
      }
      bf16x8 pfB[2], pfA[2];
      pconv(sB, dgB, &Ps[wave][1][0], pfB, laccB, ks);
      if (doA) pconv(sA, dgA, &Ps[wave][0][0], pfA, laccA, ks);
#pragma unroll
      for (int ds = 0; ds < 4; ++ds) {
        bf16x8 vf = *(const bf16x8*)&Vc[(ds * 16 + l15) * 128 + (((ks * 4 + g) ^ l15) * 8)];
        oB[0][ds] = __builtin_amdgcn_mfma_f32_16x16x32_bf16(pfB[0], vf, oB[0][ds], 0, 0, 0);
        oB[1][ds] = __builtin_amdgcn_mfma_f32_16x16x32_bf16(pfB[1], vf, oB[1][ds], 0, 0, 0);
        if (doA) {
          oA[0][ds] = __builtin_amdgcn_mfma_f32_16x16x32_bf16(pfA[0], vf, oA[0][ds], 0, 0, 0);
          oA[1][ds] = __builtin_amdgcn_mfma_f32_16x16x32_bf16(pfA[1], vf, oA[1][ds], 0, 0, 0);
        }
      }
    }
  }

  // Epilogue: normalize, transpose 16x64 halves through per-wave LDS, b128 stores.
  bf16_t* E = &Ps[wave][0][0];  // 2048 bf16 of wave-private scratch; need 16*72
  auto epi = [&](f32x4 (&o)[2][4], f32x4 (&lacc)[2], int qt) {
#pragma unroll
    for (int ms = 0; ms < 2; ++ms) {
      f32x4 linv;
#pragma unroll
      for (int ii = 0; ii < 4; ++ii) linv[ii] = 1.0f / lacc[ms][ii];
#pragma unroll
      for (int ds = 0; ds < 4; ++ds)
#pragma unroll
        for (int ii = 0; ii < 4; ++ii)
          E[(g * 4 + ii) * 72 + ds * 16 + l15] = __float2bfloat16(o[ms][ds][ii] * linv[ii]);
      // wave-private LDS, in-order DS ops -> no barrier
      bf16x8 r0 = *(const bf16x8*)&E[l15 * 72 + g * 16];
      bf16x8 r1 = *(const bf16x8*)&E[l15 * 72 + g * 16 + 8];
      int q = qt * 128 + wave * 32 + ms * 16 + l15;
      *(bf16x8*)&y[(long)(b * T + q) * 2048 + h * 64 + g * 16] = r0;
      *(bf16x8*)&y[(long)(b * T + q) * 2048 + h * 64 + g * 16 + 8] = r1;
    }
  };
  epi(oB, laccB, qtB);
  epi(oA, laccA, qtA);
}

extern "C" void kernel_launch(void* const* d_in, const int* in_sizes, int n_in,
                              void* d_out, int out_size, void* d_ws, size_t ws_size,
                              hipStream_t stream) {
  const float* x  = (const float*)d_in[0];
  const float* Wq = (const float*)d_in[1];
  const float* Wk = (const float*)d_in[2];
  const float* Wv = (const float*)d_in[3];
  const float* Wo = (const float*)d_in[4];
  float* out = (float*)d_out;
  char* ws = (char*)d_ws;

  bf16_t* xb    = (bf16_t*)(ws);                                     // 16.78 MB (reused as y)
  bf16_t* wqkvt = (bf16_t*)(ws + 16777216);                          // 12.58 MB
  bf16_t* wot   = (bf16_t*)(ws + 16777216 + 12582912);               // 8.39 MB
  bf16_t* qkvb  = (bf16_t*)(ws + 16777216 + 12582912 + 8388608);     // 25.17 MB
  bf16_t* vtb   = (bf16_t*)(ws + 16777216 + 12582912 + 8388608 + 25165824); // 4.19 MB
  bf16_t* yb = xb;  // x dead after QKV GEMM

  dim3 b32(32, 8);
  cast_f32_bf16<<<8192, 256, 0, stream>>>(x, xb, 2097152);
  wtrans_cast<<<dim3(64, 64), b32, 0, stream>>>(Wq, wqkvt, 2048);
  wtrans_cast<<<dim3(16, 64), b32, 0, stream>>>(Wk, wqkvt + 2048L * 2048, 512);
  wtrans_cast<<<dim3(16, 64), b32, 0, stream>>>(Wv, wqkvt + 2560L * 2048, 512);
  wtrans_cast<<<dim3(64, 64), b32, 0, stream>>>(Wo, wot, 2048);
  gemm_bt<bf16_t><<<dim3(24, 32), 256, 0, stream>>>(xb, wqkvt, qkvb, 4096, 3072, 2048);
  rope_kernel<<<2560, 256, 0, stream>>>(qkvb);
  transpose_v<<<dim3(64, 2, 16), b32, 0, stream>>>(qkvb, vtb);
  flash_attn<<<dim3(8, 32, 2), 256, 0, stream>>>(qkvb, vtb, yb);
  gemm_bt<float><<<dim3(16, 32), 256, 0, stream>>>(yb, wot, out, 4096, 2048, 2048);
}

// Round 4
// 313.728 us; speedup vs baseline: 1.4892x; 1.4892x over previous
//
#include <hip/hip_runtime.h>
#include <hip/hip_bf16.h>

// GQA: B=2, T=2048, C=2048, H=32, KV=8, D=64, n_rep=4, causal, RoPE base 1e4.
// Round 4: flash = round-2 single-q-tile structure (no spills) + single-barrier
// double-buffered K/V staging + raw v_exp P-conversion + packed y stores.
// (Round 3's paired q-tiles doubled live accumulators -> 450 MB scratch spill.)

typedef __hip_bfloat16 bf16_t;
typedef __bf16 bf16x8 __attribute__((ext_vector_type(8)));
typedef float f32x4 __attribute__((ext_vector_type(4)));

#define AS1 __attribute__((address_space(1)))
#define AS3 __attribute__((address_space(3)))

__device__ __forceinline__ void gload_lds16(const void* g, void* l) {
  __builtin_amdgcn_global_load_lds((const AS1 unsigned int*)g,
                                   (AS3 unsigned int*)l, 16, 0, 0);
}

__device__ __forceinline__ float fast_exp2(float x) {
#if __has_builtin(__builtin_amdgcn_exp2f)
  return __builtin_amdgcn_exp2f(x);
#else
  return exp2f(x);
#endif
}

__device__ __forceinline__ unsigned int pack_bf16_rnd(unsigned int u0, unsigned int u1) {
  // round-to-nearest(ties away) both fp32 bit patterns, pack high halves
  u0 += 0x8000u; u1 += 0x8000u;
#if __has_builtin(__builtin_amdgcn_perm)
  return __builtin_amdgcn_perm(u1, u0, 0x07060302u);
#else
  return (u1 & 0xffff0000u) | (u0 >> 16);
#endif
}

__device__ __forceinline__ void store_out(float* p, float v) { *p = v; }
__device__ __forceinline__ void store_out(bf16_t* p, float v) { *p = __float2bfloat16(v); }

// ---------------- cast x (fp32 -> bf16), vectorized ----------------
__global__ void cast_f32_bf16(const float* __restrict__ src, bf16_t* __restrict__ dst, int n4) {
  int i = blockIdx.x * blockDim.x + threadIdx.x;
  if (i >= n4) return;
  float4 v = ((const float4*)src)[i];
  bf16_t o[4] = {__float2bfloat16(v.x), __float2bfloat16(v.y),
                 __float2bfloat16(v.z), __float2bfloat16(v.w)};
  ((ushort4*)dst)[i] = *(ushort4*)o;
}

// ------------- transpose+cast weight: W[2048][ncols] f32 -> dst[n][2048] bf16 -------------
__global__ void wtrans_cast(const float* __restrict__ W, bf16_t* __restrict__ dst, int ncols) {
  __shared__ float tile[32][33];
  int tx = threadIdx.x, ty = threadIdx.y;
  int n0 = blockIdx.x * 32, k0 = blockIdx.y * 32;
#pragma unroll
  for (int i = 0; i < 4; ++i)
    tile[ty + 8 * i][tx] = W[(long)(k0 + ty + 8 * i) * ncols + n0 + tx];
  __syncthreads();
#pragma unroll
  for (int i = 0; i < 4; ++i)
    dst[(long)(n0 + ty + 8 * i) * 2048 + k0 + tx] = __float2bfloat16(tile[tx][ty + 8 * i]);
}

// ---------------- RoPE in-place, b128 vectorized ----------------
// q outputs pre-scaled by 0.125 (softmax scale) * log2(e) so flash uses raw exp2.
__global__ void rope_kernel(bf16_t* __restrict__ qkv) {
  int i = blockIdx.x * 256 + threadIdx.x;   // [row(4096)][hp(40)][oct(4)]
  int oct = i & 3;
  int rem = i >> 2;
  int hp = rem % 40;
  int row = rem / 40;
  int t = row & 2047;
  int colbase = (hp < 32) ? (hp * 64) : (2048 + (hp - 32) * 64);
  long base = (long)row * 3072 + colbase + oct * 8;
  bf16x8 x1 = *(bf16x8*)(qkv + base);
  bf16x8 x2 = *(bf16x8*)(qkv + base + 32);
  float sc = (hp < 32) ? 0.18033688011112043f : 1.0f;  // 0.125*log2(e) for q
  bf16x8 o1, o2;
#pragma unroll
  for (int jj = 0; jj < 8; ++jj) {
    int d = oct * 8 + jj;
    float inv_freq = exp2f(-(float)d * 0.4152410118074032f); // log2(10000)/32
    float ang = (float)t * inv_freq;
    float sv, cv;
    sincosf(ang, &sv, &cv);   // args up to ~2047 rad exceed HW v_sin range
    float a = __bfloat162float(((const __hip_bfloat16*)&x1)[jj]);
    float b = __bfloat162float(((const __hip_bfloat16*)&x2)[jj]);
    ((__hip_bfloat16*)&o1)[jj] = __float2bfloat16((a * cv - b * sv) * sc);
    ((__hip_bfloat16*)&o2)[jj] = __float2bfloat16((a * sv + b * cv) * sc);
  }
  *(bf16x8*)(qkv + base) = o1;
  *(bf16x8*)(qkv + base + 32) = o2;
}

// ---------------- V transpose: qkv v-cols -> vt[(b*8+kv)*64 + d][T] ----------------
__global__ void transpose_v(const bf16_t* __restrict__ qkv, bf16_t* __restrict__ vt) {
  __shared__ bf16_t tile[32][33];
  int tx = threadIdx.x, ty = threadIdx.y;
  int t0 = blockIdx.x * 32, d0 = blockIdx.y * 32, bk = blockIdx.z;
  int bb = bk >> 3, kv = bk & 7;
  const bf16_t* src = qkv + (long)(bb * 2048) * 3072 + 2560 + kv * 64;
#pragma unroll
  for (int i = 0; i < 4; ++i)
    tile[ty + 8 * i][tx] = src[(long)(t0 + ty + 8 * i) * 3072 + d0 + tx];
  __syncthreads();
#pragma unroll
  for (int i = 0; i < 4; ++i)
    vt[((long)bk * 64 + d0 + ty + 8 * i) * 2048 + t0 + tx] = tile[tx][ty + 8 * i];
}

// ---------------- GEMM: C[M][N] = A[M][K] * Bt[N][K]^T, bf16 in, fp32 acc ----------------
template <typename OutT>
__global__ __launch_bounds__(256, 2)
void gemm_bt(const bf16_t* __restrict__ A, const bf16_t* __restrict__ Bt,
             OutT* __restrict__ C, int M, int N, int K) {
  __shared__ __align__(16) bf16_t As[128 * 64];
  __shared__ __align__(16) bf16_t Bs[128 * 64];
  const int tid = threadIdx.x;
  const int wave = tid >> 6, lane = tid & 63, g = lane >> 4, l15 = lane & 15;
  const int m0 = blockIdx.y * 128, n0 = blockIdx.x * 128;
  const int mw = (wave >> 1) * 64, nw = (wave & 1) * 64;
  const bf16_t* Ab = A + (long)m0 * K;
  const bf16_t* Bb = Bt + (long)n0 * K;
  f32x4 acc[4][4] = {};
  const int nkt = K >> 6;
  for (int kt = 0; kt < nkt; ++kt) {
    __syncthreads();
#pragma unroll
    for (int i = 0; i < 4; ++i) {
      int c = i * 256 + tid;
      int row = c >> 3, pos = c & 7;
      int gcol = ((pos ^ (row & 7)) * 8);
      gload_lds16(Ab + (long)row * K + kt * 64 + gcol, &As[c * 8]);
      gload_lds16(Bb + (long)row * K + kt * 64 + gcol, &Bs[c * 8]);
    }
    __syncthreads();
#pragma unroll
    for (int ks = 0; ks < 2; ++ks) {
      bf16x8 af[4], bq[4];
#pragma unroll
      for (int i = 0; i < 4; ++i) {
        int pos = ((ks * 4 + g) ^ (l15 & 7)) * 8;
        af[i] = *(const bf16x8*)&As[(mw + i * 16 + l15) * 64 + pos];
        bq[i] = *(const bf16x8*)&Bs[(nw + i * 16 + l15) * 64 + pos];
      }
#pragma unroll
      for (int i = 0; i < 4; ++i)
#pragma unroll
        for (int j = 0; j < 4; ++j)
          acc[i][j] = __builtin_amdgcn_mfma_f32_16x16x32_bf16(af[i], bq[j], acc[i][j], 0, 0, 0);
    }
  }
#pragma unroll
  for (int i = 0; i < 4; ++i)
#pragma unroll
    for (int j = 0; j < 4; ++j) {
      int r = m0 + mw + i * 16 + g * 4;
      int cn = n0 + nw + j * 16 + l15;
#pragma unroll
      for (int ii = 0; ii < 4; ++ii)
        store_out(&C[(long)(r + ii) * N + cn], acc[i][j][ii]);
    }
}

// ---------------- Flash attention: single q-tile + dbuf staging ----------------
// Per kt: sync (drains prev prefetch) -> prefetch kt+1 into buf^1 -> compute buf.
// S^T = mfma(kf, qf) C-layout (q=lane&15) -> packed b64 P writes; l via ones-MFMA.
// LDS: Ks 2x16K + Vs 2x16K + Ps 10K = 74KB -> 2 blocks/CU.
__global__ __launch_bounds__(256, 2)
void flash_attn(const bf16_t* __restrict__ qkv, const bf16_t* __restrict__ vt,
                bf16_t* __restrict__ y) {
  constexpr int T = 2048, LDQ = 3072;
  __shared__ __align__(16) bf16_t Ks[2][128 * 64];   // [kk][d], chunk-swizzled
  __shared__ __align__(16) bf16_t Vs[2][64 * 128];   // [d][kk], chunk-swizzled
  __shared__ __align__(16) bf16_t Ps[4][1280];       // per-wave P (32x32) / epi scratch (16x72)
  const int tid = threadIdx.x, wave = tid >> 6, lane = tid & 63, g = lane >> 4, l15 = lane & 15;
  const int qt = gridDim.x - 1 - blockIdx.x;  // long blocks first
  const int h = blockIdx.y, b = blockIdx.z;
  const int kvh = h >> 2;
  const bf16_t* qbase = qkv + (long)(b * T + qt * 128) * LDQ + h * 64;
  const bf16_t* kbase = qkv + (long)(b * T) * LDQ + 2048 + kvh * 64;
  const bf16_t* vbase = vt + (long)((b * 8 + kvh) * 64) * T;

  // Q fragments (B-operand layout: n=q=l15, kdim=g*8+j)
  bf16x8 qf[2][2];
#pragma unroll
  for (int ms = 0; ms < 2; ++ms)
#pragma unroll
    for (int hh = 0; hh < 2; ++hh)
      qf[ms][hh] = *(const bf16x8*)(qbase + (long)(wave * 32 + ms * 16 + l15) * LDQ + hh * 32 + g * 8);

  bf16x8 onef;
#pragma unroll
  for (int i = 0; i < 8; ++i) onef[i] = (__bf16)1.0f;

  f32x4 o[2][4] = {};
  f32x4 lacc[2] = {};
  bf16_t* Pw = &Ps[wave][0];
  const int sw = (l15 >> 1) & 3;
  const f32x4 fz = {0.f, 0.f, 0.f, 0.f};

  auto stage = [&](int kt, int buf) {
#pragma unroll
    for (int i = 0; i < 4; ++i) {
      int c = i * 256 + tid;
      { int row = c >> 3, pos = c & 7;
        gload_lds16(kbase + (long)(kt * 128 + row) * LDQ + ((pos ^ (row & 7)) * 8),
                    &Ks[buf][c * 8]); }
      { int row = c >> 4, pos = c & 15;
        gload_lds16(vbase + (long)row * T + kt * 128 + ((pos ^ (row & 15)) * 8),
                    &Vs[buf][c * 8]); }
    }
  };

  stage(0, 0);
  const int nkt = qt + 1;
  for (int kt = 0; kt < nkt; ++kt) {
    __syncthreads();               // per-wave vmcnt(0) drain precedes barrier:
    if (kt < qt) stage(kt + 1, (kt + 1) & 1);   // buf[kt&1] ready; buf^1 free
    const bf16_t* Kc = Ks[kt & 1];
    const bf16_t* Vc = Vs[kt & 1];
    const bool diag = (kt == qt);

#pragma unroll
    for (int ks = 0; ks < 4; ++ks) {
      // ---- S^T chunk: rows k = ks*32 + nsl*16 + g*4+ii, cols q = l15 ----
      f32x4 s[2][2];
#pragma unroll
      for (int nsl = 0; nsl < 2; ++nsl) {
        int krow = ks * 32 + nsl * 16 + l15;
        bf16x8 kf0 = *(const bf16x8*)&Kc[krow * 64 + ((g ^ (l15 & 7)) * 8)];
        bf16x8 kf1 = *(const bf16x8*)&Kc[krow * 64 + (((4 + g) ^ (l15 & 7)) * 8)];
#pragma unroll
        for (int ms = 0; ms < 2; ++ms) {
          f32x4 t = __builtin_amdgcn_mfma_f32_16x16x32_bf16(kf0, qf[ms][0], fz, 0, 0, 0);
          s[ms][nsl] = __builtin_amdgcn_mfma_f32_16x16x32_bf16(kf1, qf[ms][1], t, 0, 0, 0);
        }
      }
      // ---- P = exp2(S) (q pre-scaled), mask, RNTA-pack, b64 write to wave-private Ps ----
      bf16x8 pf[2];
#pragma unroll
      for (int ms = 0; ms < 2; ++ms) {
#pragma unroll
        for (int nsl = 0; nsl < 2; ++nsl) {
          unsigned int u[4];
#pragma unroll
          for (int ii = 0; ii < 4; ++ii) {
            float p = fast_exp2(s[ms][nsl][ii]);
            if (diag && (ks * 32 + nsl * 16 + g * 4 + ii > wave * 32 + ms * 16 + l15)) p = 0.f;
            u[ii] = __builtin_bit_cast(unsigned int, p);
          }
          uint2 dw;
          dw.x = pack_bf16_rnd(u[0], u[1]);
          dw.y = pack_bf16_rnd(u[2], u[3]);
          int pp = (nsl * 2 + (g >> 1)) ^ sw;
          *(uint2*)&Pw[(ms * 16 + l15) * 32 + pp * 8 + (g & 1) * 4] = dw;
        }
        pf[ms] = *(const bf16x8*)&Pw[(ms * 16 + l15) * 32 + ((g ^ sw) * 8)];
        lacc[ms] = __builtin_amdgcn_mfma_f32_16x16x32_bf16(pf[ms], onef, lacc[ms], 0, 0, 0);
      }
      // ---- PV chunk (wave-private Ps: in-order DS ops, no barrier) ----
#pragma unroll
      for (int ds = 0; ds < 4; ++ds) {
        bf16x8 vf = *(const bf16x8*)&Vc[(ds * 16 + l15) * 128 + (((ks * 4 + g) ^ l15) * 8)];
        o[0][ds] = __builtin_amdgcn_mfma_f32_16x16x32_bf16(pf[0], vf, o[0][ds], 0, 0, 0);
        o[1][ds] = __builtin_amdgcn_mfma_f32_16x16x32_bf16(pf[1], vf, o[1][ds], 0, 0, 0);
      }
    }
  }

  // ---- epilogue: normalize, transpose 16x64 halves through wave-private LDS, b128 stores ----
  bf16_t* E = &Ps[wave][0];  // needs 16*72 = 1152 <= 1280
#pragma unroll
  for (int ms = 0; ms < 2; ++ms) {
    f32x4 linv;
#pragma unroll
    for (int ii = 0; ii < 4; ++ii) linv[ii] = 1.0f / lacc[ms][ii];
#pragma unroll
    for (int ds = 0; ds < 4; ++ds)
#pragma unroll
      for (int ii = 0; ii < 4; ++ii)
        E[(g * 4 + ii) * 72 + ds * 16 + l15] = __float2bfloat16(o[ms][ds][ii] * linv[ii]);
    // wave-private LDS, in-order DS ops -> no barrier
    bf16x8 r0 = *(const bf16x8*)&E[l15 * 72 + g * 16];
    bf16x8 r1 = *(const bf16x8*)&E[l15 * 72 + g * 16 + 8];
    int q = qt * 128 + wave * 32 + ms * 16 + l15;
    *(bf16x8*)&y[(long)(b * T + q) * 2048 + h * 64 + g * 16] = r0;
    *(bf16x8*)&y[(long)(b * T + q) * 2048 + h * 64 + g * 16 + 8] = r1;
  }
}

extern "C" void kernel_launch(void* const* d_in, const int* in_sizes, int n_in,
                              void* d_out, int out_size, void* d_ws, size_t ws_size,
                              hipStream_t stream) {
  const float* x  = (const float*)d_in[0];
  const float* Wq = (const float*)d_in[1];
  const float* Wk = (const float*)d_in[2];
  const float* Wv = (const float*)d_in[3];
  const float* Wo = (const float*)d_in[4];
  float* out = (float*)d_out;
  char* ws = (char*)d_ws;

  bf16_t* xb    = (bf16_t*)(ws);                                     // 16.78 MB (reused as y)
  bf16_t* wqkvt = (bf16_t*)(ws + 16777216);                          // 12.58 MB
  bf16_t* wot   = (bf16_t*)(ws + 16777216 + 12582912);               // 8.39 MB
  bf16_t* qkvb  = (bf16_t*)(ws + 16777216 + 12582912 + 8388608);     // 25.17 MB
  bf16_t* vtb   = (bf16_t*)(ws + 16777216 + 12582912 + 8388608 + 25165824); // 4.19 MB
  bf16_t* yb = xb;  // x dead after QKV GEMM

  dim3 b32(32, 8);
  cast_f32_bf16<<<8192, 256, 0, stream>>>(x, xb, 2097152);
  wtrans_cast<<<dim3(64, 64), b32, 0, stream>>>(Wq, wqkvt, 2048);
  wtrans_cast<<<dim3(16, 64), b32, 0, stream>>>(Wk, wqkvt + 2048L * 2048, 512);
  wtrans_cast<<<dim3(16, 64), b32, 0, stream>>>(Wv, wqkvt + 2560L * 2048, 512);
  wtrans_cast<<<dim3(64, 64), b32, 0, stream>>>(Wo, wot, 2048);
  gemm_bt<bf16_t><<<dim3(24, 32), 256, 0, stream>>>(xb, wqkvt, qkvb, 4096, 3072, 2048);
  rope_kernel<<<2560, 256, 0, stream>>>(qkvb);
  transpose_v<<<dim3(64, 2, 16), b32, 0, stream>>>(qkvb, vtb);
  flash_attn<<<dim3(16, 32, 2), 256, 0, stream>>>(qkvb, vtb, yb);
  gemm_bt<float><<<dim3(16, 32), 256, 0, stream>>>(yb, wot, out, 4096, 2048, 2048);
}

// Round 5
// 311.271 us; speedup vs baseline: 1.5009x; 1.0079x over previous
//
#include <hip/hip_runtime.h>
#include <hip/hip_bf16.h>

// GQA: B=2, T=2048, C=2048, H=32, KV=8, D=64, n_rep=4, causal, RoPE base 1e4.
// Round 5: flash 64-key k-tiles + dbuf -> 40KB LDS = 4 blocks/CU (whole grid
// resident, per-CU balanced qt mapping); launches fused 10 -> 5; HW trig rope.

typedef __hip_bfloat16 bf16_t;
typedef __bf16 bf16x8 __attribute__((ext_vector_type(8)));
typedef float f32x4 __attribute__((ext_vector_type(4)));

#define AS1 __attribute__((address_space(1)))
#define AS3 __attribute__((address_space(3)))

__device__ __forceinline__ void gload_lds16(const void* g, void* l) {
  __builtin_amdgcn_global_load_lds((const AS1 unsigned int*)g,
                                   (AS3 unsigned int*)l, 16, 0, 0);
}

__device__ __forceinline__ float fast_exp2(float x) {
#if __has_builtin(__builtin_amdgcn_exp2f)
  return __builtin_amdgcn_exp2f(x);
#else
  return exp2f(x);
#endif
}

__device__ __forceinline__ unsigned int pack_bf16_rnd(unsigned int u0, unsigned int u1) {
  u0 += 0x8000u; u1 += 0x8000u;
#if __has_builtin(__builtin_amdgcn_perm)
  return __builtin_amdgcn_perm(u1, u0, 0x07060302u);
#else
  return (u1 & 0xffff0000u) | (u0 >> 16);
#endif
}

__device__ __forceinline__ void store_out(float* p, float v) { *p = v; }
__device__ __forceinline__ void store_out(bf16_t* p, float v) { *p = __float2bfloat16(v); }

// ---------------- prep: cast x + transpose/cast all 4 weights, one launch ----------------
// blocks: [0,2048) cast (4 float4/thread); [2048,6144) Wq; [6144,10240) Wo;
// [10240,11264) Wk; [11264,12288) Wv.
__global__ void prep(const float* __restrict__ x, const float* __restrict__ Wq,
                     const float* __restrict__ Wk, const float* __restrict__ Wv,
                     const float* __restrict__ Wo, bf16_t* __restrict__ xb,
                     bf16_t* __restrict__ wqkvt, bf16_t* __restrict__ wot) {
  const int bid = blockIdx.x, tid = threadIdx.x;
  if (bid < 2048) {
#pragma unroll
    for (int k = 0; k < 4; ++k) {
      int i = bid * 1024 + k * 256 + tid;
      float4 v = ((const float4*)x)[i];
      bf16_t o[4] = {__float2bfloat16(v.x), __float2bfloat16(v.y),
                     __float2bfloat16(v.z), __float2bfloat16(v.w)};
      ((ushort4*)xb)[i] = *(ushort4*)o;
    }
    return;
  }
  const float* W; bf16_t* dst; int ncols, bx, by;
  if (bid < 6144)       { int l = bid - 2048;  W = Wq; dst = wqkvt;               ncols = 2048; bx = l & 63; by = l >> 6; }
  else if (bid < 10240) { int l = bid - 6144;  W = Wo; dst = wot;                 ncols = 2048; bx = l & 63; by = l >> 6; }
  else if (bid < 11264) { int l = bid - 10240; W = Wk; dst = wqkvt + 2048L * 2048; ncols = 512; bx = l & 15; by = l >> 4; }
  else                  { int l = bid - 11264; W = Wv; dst = wqkvt + 2560L * 2048; ncols = 512; bx = l & 15; by = l >> 4; }
  __shared__ float tile[32][33];
  const int tx = tid & 31, ty = tid >> 5;
  const int n0 = bx * 32, k0 = by * 32;
#pragma unroll
  for (int i = 0; i < 4; ++i)
    tile[ty + 8 * i][tx] = W[(long)(k0 + ty + 8 * i) * ncols + n0 + tx];
  __syncthreads();
#pragma unroll
  for (int i = 0; i < 4; ++i)
    dst[(long)(n0 + ty + 8 * i) * 2048 + k0 + tx] = __float2bfloat16(tile[tx][ty + 8 * i]);
}

// ---------------- rope (cols 0..2559) + V transpose (cols 2560..3071), one launch ----------------
// q outputs pre-scaled by 0.125 (softmax scale) * log2(e) so flash uses raw exp2.
__global__ void rope_vt(bf16_t* __restrict__ qkv, bf16_t* __restrict__ vt) {
  const int bid = blockIdx.x, tid = threadIdx.x;
  __shared__ bf16_t tile[32][33];
  if (bid < 2560) {
    int i = bid * 256 + tid;   // [row(4096)][hp(40)][oct(4)]
    int oct = i & 3;
    int rem = i >> 2;
    int hp = rem % 40;
    int row = rem / 40;
    int t = row & 2047;
    int colbase = (hp < 32) ? (hp * 64) : (2048 + (hp - 32) * 64);
    long base = (long)row * 3072 + colbase + oct * 8;
    bf16x8 x1 = *(bf16x8*)(qkv + base);
    bf16x8 x2 = *(bf16x8*)(qkv + base + 32);
    float sc = (hp < 32) ? 0.18033688011112043f : 1.0f;  // 0.125*log2(e) for q
    bf16x8 o1, o2;
#pragma unroll
    for (int jj = 0; jj < 8; ++jj) {
      int d = oct * 8 + jj;
      float inv_freq = exp2f(-(float)d * 0.4152410118074032f); // log2(10000)/32
      float ang = (float)t * inv_freq;
      // manual range reduction (rev error ~3e-5 << bf16 tol), then HW sin/cos
      float rev = ang * 0.15915494309189535f;
      float fr = (rev - rintf(rev)) * 6.283185307179586f;   // in [-pi, pi]
      float sv = __sinf(fr), cv = __cosf(fr);
      float a = __bfloat162float(((const __hip_bfloat16*)&x1)[jj]);
      float b = __bfloat162float(((const __hip_bfloat16*)&x2)[jj]);
      ((__hip_bfloat16*)&o1)[jj] = __float2bfloat16((a * cv - b * sv) * sc);
      ((__hip_bfloat16*)&o2)[jj] = __float2bfloat16((a * sv + b * cv) * sc);
    }
    *(bf16x8*)(qkv + base) = o1;
    *(bf16x8*)(qkv + base + 32) = o2;
    return;
  }
  // V transpose: qkv v-cols -> vt[(b*8+kv)*64 + d][T]
  int l = bid - 2560;            // 2048 blocks: [t0(64)][d0i(2)][bk(16)]
  int t0 = (l & 63) * 32;
  int rest = l >> 6;
  int d0 = (rest & 1) * 32;
  int bk = rest >> 1;
  int bb = bk >> 3, kv = bk & 7;
  const int tx = tid & 31, ty = tid >> 5;
  const bf16_t* src = qkv + (long)(bb * 2048) * 3072 + 2560 + kv * 64;
#pragma unroll
  for (int i = 0; i < 4; ++i)
    tile[ty + 8 * i][tx] = src[(long)(t0 + ty + 8 * i) * 3072 + d0 + tx];
  __syncthreads();
#pragma unroll
  for (int i = 0; i < 4; ++i)
    vt[((long)bk * 64 + d0 + ty + 8 * i) * 2048 + t0 + tx] = tile[tx][ty + 8 * i];
}

// ---------------- GEMM: C[M][N] = A[M][K] * Bt[N][K]^T, bf16 in, fp32 acc ----------------
template <typename OutT>
__global__ __launch_bounds__(256, 3)
void gemm_bt(const bf16_t* __restrict__ A, const bf16_t* __restrict__ Bt,
             OutT* __restrict__ C, int M, int N, int K) {
  __shared__ __align__(16) bf16_t As[128 * 64];
  __shared__ __align__(16) bf16_t Bs[128 * 64];
  const int tid = threadIdx.x;
  const int wave = tid >> 6, lane = tid & 63, g = lane >> 4, l15 = lane & 15;
  const int m0 = blockIdx.y * 128, n0 = blockIdx.x * 128;
  const int mw = (wave >> 1) * 64, nw = (wave & 1) * 64;
  const bf16_t* Ab = A + (long)m0 * K;
  const bf16_t* Bb = Bt + (long)n0 * K;
  f32x4 acc[4][4] = {};
  const int nkt = K >> 6;
  for (int kt = 0; kt < nkt; ++kt) {
    __syncthreads();
#pragma unroll
    for (int i = 0; i < 4; ++i) {
      int c = i * 256 + tid;
      int row = c >> 3, pos = c & 7;
      int gcol = ((pos ^ (row & 7)) * 8);
      gload_lds16(Ab + (long)row * K + kt * 64 + gcol, &As[c * 8]);
      gload_lds16(Bb + (long)row * K + kt * 64 + gcol, &Bs[c * 8]);
    }
    __syncthreads();
#pragma unroll
    for (int ks = 0; ks < 2; ++ks) {
      bf16x8 af[4], bq[4];
#pragma unroll
      for (int i = 0; i < 4; ++i) {
        int pos = ((ks * 4 + g) ^ (l15 & 7)) * 8;
        af[i] = *(const bf16x8*)&As[(mw + i * 16 + l15) * 64 + pos];
        bq[i] = *(const bf16x8*)&Bs[(nw + i * 16 + l15) * 64 + pos];
      }
#pragma unroll
      for (int i = 0; i < 4; ++i)
#pragma unroll
        for (int j = 0; j < 4; ++j)
          acc[i][j] = __builtin_amdgcn_mfma_f32_16x16x32_bf16(af[i], bq[j], acc[i][j], 0, 0, 0);
    }
  }
#pragma unroll
  for (int i = 0; i < 4; ++i)
#pragma unroll
    for (int j = 0; j < 4; ++j) {
      int r = m0 + mw + i * 16 + g * 4;
      int cn = n0 + nw + j * 16 + l15;
#pragma unroll
      for (int ii = 0; ii < 4; ++ii)
        store_out(&C[(long)(r + ii) * N + cn], acc[i][j][ii]);
    }
}

// ---------------- Flash attention: 64-key tiles, dbuf, 4 blocks/CU ----------------
// Block j -> qt via (j<8)?15-j:j-8 (per-CU balanced under round-robin dispatch).
// Per kt: sync (drains prefetch) -> prefetch kt+1 into buf^1 -> compute buf.
// S^T = mfma(kf, qf) C-layout (q=lane&15) -> packed b64 P writes; l via ones-MFMA.
// LDS: Ks 2x8K + Vs 2x8K + Ps 8K = 40960 B -> exactly 4 blocks/CU.
__global__ __launch_bounds__(256, 4)
void flash_attn(const bf16_t* __restrict__ qkv, const bf16_t* __restrict__ vt,
                bf16_t* __restrict__ y) {
  constexpr int T = 2048, LDQ = 3072;
  __shared__ __align__(16) bf16_t Ks[2][64 * 64];   // [kk][d], chunk-swizzled
  __shared__ __align__(16) bf16_t Vs[2][64 * 64];   // [d][kk], chunk-swizzled
  __shared__ __align__(16) bf16_t Ps[4][1024];      // per-wave P (32x32)
  const int tid = threadIdx.x, wave = tid >> 6, lane = tid & 63, g = lane >> 4, l15 = lane & 15;
  const int j = blockIdx.x;
  const int qt = (j < 8) ? (15 - j) : (j - 8);
  const int h = blockIdx.y, b = blockIdx.z;
  const int kvh = h >> 2;
  const bf16_t* qbase = qkv + (long)(b * T + qt * 128) * LDQ + h * 64;
  const bf16_t* kbase = qkv + (long)(b * T) * LDQ + 2048 + kvh * 64;
  const bf16_t* vbase = vt + (long)((b * 8 + kvh) * 64) * T;

  // Q fragments (B-operand layout: n=q=l15, kdim=g*8+jj)
  bf16x8 qf[2][2];
#pragma unroll
  for (int ms = 0; ms < 2; ++ms)
#pragma unroll
    for (int hh = 0; hh < 2; ++hh)
      qf[ms][hh] = *(const bf16x8*)(qbase + (long)(wave * 32 + ms * 16 + l15) * LDQ + hh * 32 + g * 8);

  bf16x8 onef;
#pragma unroll
  for (int i = 0; i < 8; ++i) onef[i] = (__bf16)1.0f;

  f32x4 o[2][4] = {};
  f32x4 lacc[2] = {};
  bf16_t* Pw = &Ps[wave][0];
  const int sw = (l15 >> 1) & 3;
  const f32x4 fz = {0.f, 0.f, 0.f, 0.f};

  auto stage = [&](int kt, int buf) {
#pragma unroll
    for (int i = 0; i < 2; ++i) {
      int c = i * 256 + tid;           // 512 chunk-loads per 64x64 tile
      int row = c >> 3, pos = c & 7;
      gload_lds16(kbase + (long)(kt * 64 + row) * LDQ + ((pos ^ (row & 7)) * 8),
                  &Ks[buf][c * 8]);
      gload_lds16(vbase + (long)row * T + kt * 64 + ((pos ^ (row & 7)) * 8),
                  &Vs[buf][c * 8]);
    }
  };

  stage(0, 0);
  const int nkt = 2 * qt + 2;
  for (int kt = 0; kt < nkt; ++kt) {
    __syncthreads();               // vmcnt(0) drain precedes barrier: buf[kt&1] ready
    if (kt + 1 < nkt) stage(kt + 1, (kt + 1) & 1);
    const bf16_t* Kc = Ks[kt & 1];
    const bf16_t* Vc = Vs[kt & 1];
    const int dk = kt - 2 * qt;        // >=0 only on the two diagonal tiles
    const bool diag = (dk >= 0);

#pragma unroll
    for (int ks = 0; ks < 2; ++ks) {
      // ---- S^T chunk: rows k = ks*32 + nsl*16 + g*4+ii, cols q = l15 ----
      f32x4 s[2][2];
#pragma unroll
      for (int nsl = 0; nsl < 2; ++nsl) {
        int krow = ks * 32 + nsl * 16 + l15;
        bf16x8 kf0 = *(const bf16x8*)&Kc[krow * 64 + ((g ^ (l15 & 7)) * 8)];
        bf16x8 kf1 = *(const bf16x8*)&Kc[krow * 64 + (((4 + g) ^ (l15 & 7)) * 8)];
#pragma unroll
        for (int ms = 0; ms < 2; ++ms) {
          f32x4 t = __builtin_amdgcn_mfma_f32_16x16x32_bf16(kf0, qf[ms][0], fz, 0, 0, 0);
          s[ms][nsl] = __builtin_amdgcn_mfma_f32_16x16x32_bf16(kf1, qf[ms][1], t, 0, 0, 0);
        }
      }
      // ---- P = exp2(S) (q pre-scaled), mask, RNTA-pack, b64 write to wave-private Ps ----
      bf16x8 pf[2];
#pragma unroll
      for (int ms = 0; ms < 2; ++ms) {
#pragma unroll
        for (int nsl = 0; nsl < 2; ++nsl) {
          unsigned int u[4];
#pragma unroll
          for (int ii = 0; ii < 4; ++ii) {
            float p = fast_exp2(s[ms][nsl][ii]);
            if (diag && (dk * 64 + ks * 32 + nsl * 16 + g * 4 + ii >
                         wave * 32 + ms * 16 + l15)) p = 0.f;
            u[ii] = __builtin_bit_cast(unsigned int, p);
          }
          uint2 dw;
          dw.x = pack_bf16_rnd(u[0], u[1]);
          dw.y = pack_bf16_rnd(u[2], u[3]);
          int pp = (nsl * 2 + (g >> 1)) ^ sw;
          *(uint2*)&Pw[(ms * 16 + l15) * 32 + pp * 8 + (g & 1) * 4] = dw;
        }
        pf[ms] = *(const bf16x8*)&Pw[(ms * 16 + l15) * 32 + ((g ^ sw) * 8)];
        lacc[ms] = __builtin_amdgcn_mfma_f32_16x16x32_bf16(pf[ms], onef, lacc[ms], 0, 0, 0);
      }
      // ---- PV chunk (wave-private Ps: in-order DS ops, no barrier) ----
#pragma unroll
      for (int ds = 0; ds < 4; ++ds) {
        bf16x8 vf = *(const bf16x8*)&Vc[(ds * 16 + l15) * 64 + (((ks * 4 + g) ^ (l15 & 7)) * 8)];
        o[0][ds] = __builtin_amdgcn_mfma_f32_16x16x32_bf16(pf[0], vf, o[0][ds], 0, 0, 0);
        o[1][ds] = __builtin_amdgcn_mfma_f32_16x16x32_bf16(pf[1], vf, o[1][ds], 0, 0, 0);
      }
    }
  }

  // ---- epilogue: normalize, transpose 16x64 halves via LDS (reuse Vs), b128 stores ----
  __syncthreads();                         // all waves done reading Ks/Vs
  bf16_t* E = (bf16_t*)&Vs[0][0] + wave * 1152;  // 16*72 = 1152 per wave
#pragma unroll
  for (int ms = 0; ms < 2; ++ms) {
    f32x4 linv;
#pragma unroll
    for (int ii = 0; ii < 4; ++ii) linv[ii] = 1.0f / lacc[ms][ii];
#pragma unroll
    for (int ds = 0; ds < 4; ++ds)
#pragma unroll
      for (int ii = 0; ii < 4; ++ii)
        E[(g * 4 + ii) * 72 + ds * 16 + l15] = __float2bfloat16(o[ms][ds][ii] * linv[ii]);
    // wave-private region, in-order DS ops -> no barrier
    bf16x8 r0 = *(const bf16x8*)&E[l15 * 72 + g * 16];
    bf16x8 r1 = *(const bf16x8*)&E[l15 * 72 + g * 16 + 8];
    int q = qt * 128 + wave * 32 + ms * 16 + l15;
    *(bf16x8*)&y[(long)(b * T + q) * 2048 + h * 64 + g * 16] = r0;
    *(bf16x8*)&y[(long)(b * T + q) * 2048 + h * 64 + g * 16 + 8] = r1;
  }
}

extern "C" void kernel_launch(void* const* d_in, const int* in_sizes, int n_in,
                              void* d_out, int out_size, void* d_ws, size_t ws_size,
                              hipStream_t stream) {
  const float* x  = (const float*)d_in[0];
  const float* Wq = (const float*)d_in[1];
  const float* Wk = (const float*)d_in[2];
  const float* Wv = (const float*)d_in[3];
  const float* Wo = (const float*)d_in[4];
  float* out = (float*)d_out;
  char* ws = (char*)d_ws;

  bf16_t* xb    = (bf16_t*)(ws);                                     // 16.78 MB (reused as y)
  bf16_t* wqkvt = (bf16_t*)(ws + 16777216);                          // 12.58 MB
  bf16_t* wot   = (bf16_t*)(ws + 16777216 + 12582912);               // 8.39 MB
  bf16_t* qkvb  = (bf16_t*)(ws + 16777216 + 12582912 + 8388608);     // 25.17 MB
  bf16_t* vtb   = (bf16_t*)(ws + 16777216 + 12582912 + 8388608 + 25165824); // 4.19 MB
  bf16_t* yb = xb;  // x dead after QKV GEMM

  prep<<<12288, 256, 0, stream>>>(x, Wq, Wk, Wv, Wo, xb, wqkvt, wot);
  gemm_bt<bf16_t><<<dim3(24, 32), 256, 0, stream>>>(xb, wqkvt, qkvb, 4096, 3072, 2048);
  rope_vt<<<4608, 256, 0, stream>>>(qkvb, vtb);
  flash_attn<<<dim3(16, 32, 2), 256, 0, stream>>>(qkvb, vtb, yb);
  gemm_bt<float><<<dim3(16, 32), 256, 0, stream>>>(yb, wot, out, 4096, 2048, 2048);
}

// Round 6
// 282.756 us; speedup vs baseline: 1.6523x; 1.1008x over previous
//
#include <hip/hip_runtime.h>
#include <hip/hip_bf16.h>

// GQA: B=2, T=2048, C=2048, H=32, KV=8, D=64, n_rep=4, causal, RoPE base 1e4.
// Round 6: fix flash per-CU load balance. Blocks {n, n+256, n+512, n+768} land
// on the same CU (same x in grid(16,32,2)); round-5 gave them all the same qt
// -> slowest CU did 136 k-tiles while others idled (Occupancy 19.7%, dur flat).
// Now qt flips via (h>>4)&1 so every CU gets {qt, 15-qt} x2 = exactly 68 tiles.

typedef __hip_bfloat16 bf16_t;
typedef __bf16 bf16x8 __attribute__((ext_vector_type(8)));
typedef float f32x4 __attribute__((ext_vector_type(4)));

#define AS1 __attribute__((address_space(1)))
#define AS3 __attribute__((address_space(3)))

__device__ __forceinline__ void gload_lds16(const void* g, void* l) {
  __builtin_amdgcn_global_load_lds((const AS1 unsigned int*)g,
                                   (AS3 unsigned int*)l, 16, 0, 0);
}

__device__ __forceinline__ float fast_exp2(float x) {
#if __has_builtin(__builtin_amdgcn_exp2f)
  return __builtin_amdgcn_exp2f(x);
#else
  return exp2f(x);
#endif
}

__device__ __forceinline__ unsigned int pack_bf16_rnd(unsigned int u0, unsigned int u1) {
  u0 += 0x8000u; u1 += 0x8000u;
#if __has_builtin(__builtin_amdgcn_perm)
  return __builtin_amdgcn_perm(u1, u0, 0x07060302u);
#else
  return (u1 & 0xffff0000u) | (u0 >> 16);
#endif
}

__device__ __forceinline__ void store_out(float* p, float v) { *p = v; }
__device__ __forceinline__ void store_out(bf16_t* p, float v) { *p = __float2bfloat16(v); }

// ---------------- prep: cast x + transpose/cast all 4 weights, one launch ----------------
__global__ void prep(const float* __restrict__ x, const float* __restrict__ Wq,
                     const float* __restrict__ Wk, const float* __restrict__ Wv,
                     const float* __restrict__ Wo, bf16_t* __restrict__ xb,
                     bf16_t* __restrict__ wqkvt, bf16_t* __restrict__ wot) {
  const int bid = blockIdx.x, tid = threadIdx.x;
  if (bid < 2048) {
#pragma unroll
    for (int k = 0; k < 4; ++k) {
      int i = bid * 1024 + k * 256 + tid;
      float4 v = ((const float4*)x)[i];
      bf16_t o[4] = {__float2bfloat16(v.x), __float2bfloat16(v.y),
                     __float2bfloat16(v.z), __float2bfloat16(v.w)};
      ((ushort4*)xb)[i] = *(ushort4*)o;
    }
    return;
  }
  const float* W; bf16_t* dst; int ncols, bx, by;
  if (bid < 6144)       { int l = bid - 2048;  W = Wq; dst = wqkvt;               ncols = 2048; bx = l & 63; by = l >> 6; }
  else if (bid < 10240) { int l = bid - 6144;  W = Wo; dst = wot;                 ncols = 2048; bx = l & 63; by = l >> 6; }
  else if (bid < 11264) { int l = bid - 10240; W = Wk; dst = wqkvt + 2048L * 2048; ncols = 512; bx = l & 15; by = l >> 4; }
  else                  { int l = bid - 11264; W = Wv; dst = wqkvt + 2560L * 2048; ncols = 512; bx = l & 15; by = l >> 4; }
  __shared__ float tile[32][33];
  const int tx = tid & 31, ty = tid >> 5;
  const int n0 = bx * 32, k0 = by * 32;
#pragma unroll
  for (int i = 0; i < 4; ++i)
    tile[ty + 8 * i][tx] = W[(long)(k0 + ty + 8 * i) * ncols + n0 + tx];
  __syncthreads();
#pragma unroll
  for (int i = 0; i < 4; ++i)
    dst[(long)(n0 + ty + 8 * i) * 2048 + k0 + tx] = __float2bfloat16(tile[tx][ty + 8 * i]);
}

// ---------------- rope (cols 0..2559) + V transpose (cols 2560..3071), one launch ----------------
// q outputs pre-scaled by 0.125 (softmax scale) * log2(e) so flash uses raw exp2.
__global__ void rope_vt(bf16_t* __restrict__ qkv, bf16_t* __restrict__ vt) {
  const int bid = blockIdx.x, tid = threadIdx.x;
  __shared__ bf16_t tile[32][33];
  if (bid < 2560) {
    int i = bid * 256 + tid;   // [row(4096)][hp(40)][oct(4)]
    int oct = i & 3;
    int rem = i >> 2;
    int hp = rem % 40;
    int row = rem / 40;
    int t = row & 2047;
    int colbase = (hp < 32) ? (hp * 64) : (2048 + (hp - 32) * 64);
    long base = (long)row * 3072 + colbase + oct * 8;
    bf16x8 x1 = *(bf16x8*)(qkv + base);
    bf16x8 x2 = *(bf16x8*)(qkv + base + 32);
    float sc = (hp < 32) ? 0.18033688011112043f : 1.0f;  // 0.125*log2(e) for q
    bf16x8 o1, o2;
#pragma unroll
    for (int jj = 0; jj < 8; ++jj) {
      int d = oct * 8 + jj;
      float inv_freq = exp2f(-(float)d * 0.4152410118074032f); // log2(10000)/32
      float ang = (float)t * inv_freq;
      // manual range reduction (rev error ~3e-5 << bf16 tol), then HW sin/cos
      float rev = ang * 0.15915494309189535f;
      float fr = (rev - rintf(rev)) * 6.283185307179586f;   // in [-pi, pi]
      float sv = __sinf(fr), cv = __cosf(fr);
      float a = __bfloat162float(((const __hip_bfloat16*)&x1)[jj]);
      float b = __bfloat162float(((const __hip_bfloat16*)&x2)[jj]);
      ((__hip_bfloat16*)&o1)[jj] = __float2bfloat16((a * cv - b * sv) * sc);
      ((__hip_bfloat16*)&o2)[jj] = __float2bfloat16((a * sv + b * cv) * sc);
    }
    *(bf16x8*)(qkv + base) = o1;
    *(bf16x8*)(qkv + base + 32) = o2;
    return;
  }
  // V transpose: qkv v-cols -> vt[(b*8+kv)*64 + d][T]
  int l = bid - 2560;            // 2048 blocks: [t0(64)][d0i(2)][bk(16)]
  int t0 = (l & 63) * 32;
  int rest = l >> 6;
  int d0 = (rest & 1) * 32;
  int bk = rest >> 1;
  int bb = bk >> 3, kv = bk & 7;
  const int tx = tid & 31, ty = tid >> 5;
  const bf16_t* src = qkv + (long)(bb * 2048) * 3072 + 2560 + kv * 64;
#pragma unroll
  for (int i = 0; i < 4; ++i)
    tile[ty + 8 * i][tx] = src[(long)(t0 + ty + 8 * i) * 3072 + d0 + tx];
  __syncthreads();
#pragma unroll
  for (int i = 0; i < 4; ++i)
    vt[((long)bk * 64 + d0 + ty + 8 * i) * 2048 + t0 + tx] = tile[tx][ty + 8 * i];
}

// ---------------- GEMM: C[M][N] = A[M][K] * Bt[N][K]^T, bf16 in, fp32 acc ----------------
template <typename OutT>
__global__ __launch_bounds__(256, 3)
void gemm_bt(const bf16_t* __restrict__ A, const bf16_t* __restrict__ Bt,
             OutT* __restrict__ C, int M, int N, int K) {
  __shared__ __align__(16) bf16_t As[128 * 64];
  __shared__ __align__(16) bf16_t Bs[128 * 64];
  const int tid = threadIdx.x;
  const int wave = tid >> 6, lane = tid & 63, g = lane >> 4, l15 = lane & 15;
  const int m0 = blockIdx.y * 128, n0 = blockIdx.x * 128;
  const int mw = (wave >> 1) * 64, nw = (wave & 1) * 64;
  const bf16_t* Ab = A + (long)m0 * K;
  const bf16_t* Bb = Bt + (long)n0 * K;
  f32x4 acc[4][4] = {};
  const int nkt = K >> 6;
  for (int kt = 0; kt < nkt; ++kt) {
    __syncthreads();
#pragma unroll
    for (int i = 0; i < 4; ++i) {
      int c = i * 256 + tid;
      int row = c >> 3, pos = c & 7;
      int gcol = ((pos ^ (row & 7)) * 8);
      gload_lds16(Ab + (long)row * K + kt * 64 + gcol, &As[c * 8]);
      gload_lds16(Bb + (long)row * K + kt * 64 + gcol, &Bs[c * 8]);
    }
    __syncthreads();
#pragma unroll
    for (int ks = 0; ks < 2; ++ks) {
      bf16x8 af[4], bq[4];
#pragma unroll
      for (int i = 0; i < 4; ++i) {
        int pos = ((ks * 4 + g) ^ (l15 & 7)) * 8;
        af[i] = *(const bf16x8*)&As[(mw + i * 16 + l15) * 64 + pos];
        bq[i] = *(const bf16x8*)&Bs[(nw + i * 16 + l15) * 64 + pos];
      }
#pragma unroll
      for (int i = 0; i < 4; ++i)
#pragma unroll
        for (int j = 0; j < 4; ++j)
          acc[i][j] = __builtin_amdgcn_mfma_f32_16x16x32_bf16(af[i], bq[j], acc[i][j], 0, 0, 0);
    }
  }
#pragma unroll
  for (int i = 0; i < 4; ++i)
#pragma unroll
    for (int j = 0; j < 4; ++j) {
      int r = m0 + mw + i * 16 + g * 4;
      int cn = n0 + nw + j * 16 + l15;
#pragma unroll
      for (int ii = 0; ii < 4; ++ii)
        store_out(&C[(long)(r + ii) * N + cn], acc[i][j][ii]);
    }
}

// ---------------- Flash attention: 64-key tiles, dbuf, 4 blocks/CU, CU-balanced ----------------
// qt0 = (x<8)?(15-x):(x-8); flipped by (h>>4)&1 so a CU's 4 blocks (same x,
// h differing by 16, both b) get {qt, 15-qt} x2 -> 68 k-tiles per CU, uniform.
// LDS: Ks 2x8K + Vs 2x8K + Ps 8K = 40960 B -> exactly 4 blocks/CU.
__global__ __launch_bounds__(256, 4)
void flash_attn(const bf16_t* __restrict__ qkv, const bf16_t* __restrict__ vt,
                bf16_t* __restrict__ y) {
  constexpr int T = 2048, LDQ = 3072;
  __shared__ __align__(16) bf16_t Ks[2][64 * 64];   // [kk][d], chunk-swizzled
  __shared__ __align__(16) bf16_t Vs[2][64 * 64];   // [d][kk], chunk-swizzled
  __shared__ __align__(16) bf16_t Ps[4][1024];      // per-wave P (32x32)
  const int tid = threadIdx.x, wave = tid >> 6, lane = tid & 63, g = lane >> 4, l15 = lane & 15;
  const int j = blockIdx.x;
  const int h = blockIdx.y, b = blockIdx.z;
  const int qt0 = (j < 8) ? (15 - j) : (j - 8);
  const int qt = ((h >> 4) & 1) ? (15 - qt0) : qt0;   // per-CU balance (see header)
  const int kvh = h >> 2;
  const bf16_t* qbase = qkv + (long)(b * T + qt * 128) * LDQ + h * 64;
  const bf16_t* kbase = qkv + (long)(b * T) * LDQ + 2048 + kvh * 64;
  const bf16_t* vbase = vt + (long)((b * 8 + kvh) * 64) * T;

  // Q fragments (B-operand layout: n=q=l15, kdim=g*8+jj)
  bf16x8 qf[2][2];
#pragma unroll
  for (int ms = 0; ms < 2; ++ms)
#pragma unroll
    for (int hh = 0; hh < 2; ++hh)
      qf[ms][hh] = *(const bf16x8*)(qbase + (long)(wave * 32 + ms * 16 + l15) * LDQ + hh * 32 + g * 8);

  bf16x8 onef;
#pragma unroll
  for (int i = 0; i < 8; ++i) onef[i] = (__bf16)1.0f;

  f32x4 o[2][4] = {};
  f32x4 lacc[2] = {};
  bf16_t* Pw = &Ps[wave][0];
  const int sw = (l15 >> 1) & 3;
  const f32x4 fz = {0.f, 0.f, 0.f, 0.f};

  auto stage = [&](int kt, int buf) {
#pragma unroll
    for (int i = 0; i < 2; ++i) {
      int c = i * 256 + tid;           // 512 chunk-loads per 64x64 tile
      int row = c >> 3, pos = c & 7;
      gload_lds16(kbase + (long)(kt * 64 + row) * LDQ + ((pos ^ (row & 7)) * 8),
                  &Ks[buf][c * 8]);
      gload_lds16(vbase + (long)row * T + kt * 64 + ((pos ^ (row & 7)) * 8),
                  &Vs[buf][c * 8]);
    }
  };

  stage(0, 0);
  const int nkt = 2 * qt + 2;
  for (int kt = 0; kt < nkt; ++kt) {
    __syncthreads();               // vmcnt(0) drain precedes barrier: buf[kt&1] ready
    if (kt + 1 < nkt) stage(kt + 1, (kt + 1) & 1);
    const bf16_t* Kc = Ks[kt & 1];
    const bf16_t* Vc = Vs[kt & 1];
    const int dk = kt - 2 * qt;        // >=0 only on the two diagonal tiles
    const bool diag = (dk >= 0);

#pragma unroll
    for (int ks = 0; ks < 2; ++ks) {
      // ---- S^T chunk: rows k = ks*32 + nsl*16 + g*4+ii, cols q = l15 ----
      f32x4 s[2][2];
#pragma unroll
      for (int nsl = 0; nsl < 2; ++nsl) {
        int krow = ks * 32 + nsl * 16 + l15;
        bf16x8 kf0 = *(const bf16x8*)&Kc[krow * 64 + ((g ^ (l15 & 7)) * 8)];
        bf16x8 kf1 = *(const bf16x8*)&Kc[krow * 64 + (((4 + g) ^ (l15 & 7)) * 8)];
#pragma unroll
        for (int ms = 0; ms < 2; ++ms) {
          f32x4 t = __builtin_amdgcn_mfma_f32_16x16x32_bf16(kf0, qf[ms][0], fz, 0, 0, 0);
          s[ms][nsl] = __builtin_amdgcn_mfma_f32_16x16x32_bf16(kf1, qf[ms][1], t, 0, 0, 0);
        }
      }
      // ---- P = exp2(S) (q pre-scaled), mask, RNTA-pack, b64 write to wave-private Ps ----
      bf16x8 pf[2];
#pragma unroll
      for (int ms = 0; ms < 2; ++ms) {
#pragma unroll
        for (int nsl = 0; nsl < 2; ++nsl) {
          unsigned int u[4];
#pragma unroll
          for (int ii = 0; ii < 4; ++ii) {
            float p = fast_exp2(s[ms][nsl][ii]);
            if (diag && (dk * 64 + ks * 32 + nsl * 16 + g * 4 + ii >
                         wave * 32 + ms * 16 + l15)) p = 0.f;
            u[ii] = __builtin_bit_cast(unsigned int, p);
          }
          uint2 dw;
          dw.x = pack_bf16_rnd(u[0], u[1]);
          dw.y = pack_bf16_rnd(u[2], u[3]);
          int pp = (nsl * 2 + (g >> 1)) ^ sw;
          *(uint2*)&Pw[(ms * 16 + l15) * 32 + pp * 8 + (g & 1) * 4] = dw;
        }
        pf[ms] = *(const bf16x8*)&Pw[(ms * 16 + l15) * 32 + ((g ^ sw) * 8)];
        lacc[ms] = __builtin_amdgcn_mfma_f32_16x16x32_bf16(pf[ms], onef, lacc[ms], 0, 0, 0);
      }
      // ---- PV chunk (wave-private Ps: in-order DS ops, no barrier) ----
#pragma unroll
      for (int ds = 0; ds < 4; ++ds) {
        bf16x8 vf = *(const bf16x8*)&Vc[(ds * 16 + l15) * 64 + (((ks * 4 + g) ^ (l15 & 7)) * 8)];
        o[0][ds] = __builtin_amdgcn_mfma_f32_16x16x32_bf16(pf[0], vf, o[0][ds], 0, 0, 0);
        o[1][ds] = __builtin_amdgcn_mfma_f32_16x16x32_bf16(pf[1], vf, o[1][ds], 0, 0, 0);
      }
    }
  }

  // ---- epilogue: normalize, transpose 16x64 halves via LDS (reuse Vs), b128 stores ----
  __syncthreads();                         // all waves done reading Ks/Vs
  bf16_t* E = (bf16_t*)&Vs[0][0] + wave * 1152;  // 16*72 = 1152 per wave
#pragma unroll
  for (int ms = 0; ms < 2; ++ms) {
    f32x4 linv;
#pragma unroll
    for (int ii = 0; ii < 4; ++ii) linv[ii] = 1.0f / lacc[ms][ii];
#pragma unroll
    for (int ds = 0; ds < 4; ++ds)
#pragma unroll
      for (int ii = 0; ii < 4; ++ii)
        E[(g * 4 + ii) * 72 + ds * 16 + l15] = __float2bfloat16(o[ms][ds][ii] * linv[ii]);
    // wave-private region, in-order DS ops -> no barrier
    bf16x8 r0 = *(const bf16x8*)&E[l15 * 72 + g * 16];
    bf16x8 r1 = *(const bf16x8*)&E[l15 * 72 + g * 16 + 8];
    int q = qt * 128 + wave * 32 + ms * 16 + l15;
    *(bf16x8*)&y[(long)(b * T + q) * 2048 + h * 64 + g * 16] = r0;
    *(bf16x8*)&y[(long)(b * T + q) * 2048 + h * 64 + g * 16 + 8] = r1;
  }
}

extern "C" void kernel_launch(void* const* d_in, const int* in_sizes, int n_in,
                              void* d_out, int out_size, void* d_ws, size_t ws_size,
                              hipStream_t stream) {
  const float* x  = (const float*)d_in[0];
  const float* Wq = (const float*)d_in[1];
  const float* Wk = (const float*)d_in[2];
  const float* Wv = (const float*)d_in[3];
  const float* Wo = (const float*)d_in[4];
  float* out = (float*)d_out;
  char* ws = (char*)d_ws;

  bf16_t* xb    = (bf16_t*)(ws);                                     // 16.78 MB (reused as y)
  bf16_t* wqkvt = (bf16_t*)(ws + 16777216);                          // 12.58 MB
  bf16_t* wot   = (bf16_t*)(ws + 16777216 + 12582912);               // 8.39 MB
  bf16_t* qkvb  = (bf16_t*)(ws + 16777216 + 12582912 + 8388608);     // 25.17 MB
  bf16_t* vtb   = (bf16_t*)(ws + 16777216 + 12582912 + 8388608 + 25165824); // 4.19 MB
  bf16_t* yb = xb;  // x dead after QKV GEMM

  prep<<<12288, 256, 0, stream>>>(x, Wq, Wk, Wv, Wo, xb, wqkvt, wot);
  gemm_bt<bf16_t><<<dim3(24, 32), 256, 0, stream>>>(xb, wqkvt, qkvb, 4096, 3072, 2048);
  rope_vt<<<4608, 256, 0, stream>>>(qkvb, vtb);
  flash_attn<<<dim3(16, 32, 2), 256, 0, stream>>>(qkvb, vtb, yb);
  gemm_bt<float><<<dim3(16, 32), 256, 0, stream>>>(yb, wot, out, 4096, 2048, 2048);
}